// Round 1
// baseline (2755.676 us; speedup 1.0000x reference)
//
#include <hip/hip_runtime.h>

#define FP_DIM 6144
#define RTOL 1e-5f
#define ATOL 1e-8f

#define BM 128
#define BN 128
#define BK 32
#define LDT 40   // padded LDS row stride in halves (80 B, breaks 8-way bank conflict)

typedef _Float16 half8 __attribute__((ext_vector_type(8)));
typedef float f32x4 __attribute__((ext_vector_type(4)));

// ---------------- Kernel 1: prep queries ----------------
// Per block (one query q): norms of query & truth, thresh = cos(q,t),
// effective one-sided threshold tq = thresh - (ATOL + RTOL*|thresh|),
// normalized query row in fp16 -> ws, out[q] = -1.
__global__ __launch_bounds__(256) void prep_q(
    const float* __restrict__ queries, const float* __restrict__ truths,
    _Float16* __restrict__ qn, float* __restrict__ tq, int* __restrict__ out) {
  const int q = blockIdx.x;
  const float* qr = queries + (size_t)q * FP_DIM;
  const float* tr = truths  + (size_t)q * FP_DIM;

  float sq = 0.f, st = 0.f, sd = 0.f;
  for (int j = threadIdx.x * 4; j < FP_DIM; j += 256 * 4) {
    float4 a = *(const float4*)(qr + j);
    float4 b = *(const float4*)(tr + j);
    sq += a.x * a.x + a.y * a.y + a.z * a.z + a.w * a.w;
    st += b.x * b.x + b.y * b.y + b.z * b.z + b.w * b.w;
    sd += a.x * b.x + a.y * b.y + a.z * b.z + a.w * b.w;
  }
  for (int d = 1; d < 64; d <<= 1) {
    sq += __shfl_xor(sq, d);
    st += __shfl_xor(st, d);
    sd += __shfl_xor(sd, d);
  }
  __shared__ float red[3][4];
  __shared__ float s_invq;
  const int wave = threadIdx.x >> 6;
  if ((threadIdx.x & 63) == 0) { red[0][wave] = sq; red[1][wave] = st; red[2][wave] = sd; }
  __syncthreads();
  if (threadIdx.x == 0) {
    float SQ = red[0][0] + red[0][1] + red[0][2] + red[0][3];
    float ST = red[1][0] + red[1][1] + red[1][2] + red[1][3];
    float SD = red[2][0] + red[2][1] + red[2][2] + red[2][3];
    float nq = fmaxf(sqrtf(SQ), 1e-12f);
    float nt = fmaxf(sqrtf(ST), 1e-12f);
    float th = SD / (nq * nt);
    tq[q] = th - (ATOL + RTOL * fabsf(th));
    out[q] = -1;                       // counts are (#ge) - 1
    s_invq = 1.0f / nq;
  }
  __syncthreads();
  const float invq = s_invq;
  _Float16* qd = qn + (size_t)q * FP_DIM;
  for (int j = threadIdx.x * 4; j < FP_DIM; j += 256 * 4) {
    float4 a = *(const float4*)(qr + j);
    union { _Float16 h[4]; uint2 u; } pk;
    pk.h[0] = (_Float16)(a.x * invq);
    pk.h[1] = (_Float16)(a.y * invq);
    pk.h[2] = (_Float16)(a.z * invq);
    pk.h[3] = (_Float16)(a.w * invq);
    *(uint2*)(qd + j) = pk.u;
  }
}

// ---------------- Kernel 2: fused GEMM + count ----------------
// C[i][q] = dot(data_i_fp16, qn_q); count (C * inv_norm_i >= tq[q]).
// inv_norm_i computed for free from A staging (each block reads its 128 rows fully).
__global__ __launch_bounds__(256) void rank_gemm(
    const float* __restrict__ data, const _Float16* __restrict__ qn,
    const float* __restrict__ tq, int* __restrict__ out, int ND) {
  __shared__ __align__(16) _Float16 sA[BM * LDT];
  __shared__ __align__(16) _Float16 sB[BN * LDT];
  __shared__ float sNrm[BM];
  __shared__ int sCnt[BN];

  const int t = threadIdx.x;
  const int n0 = blockIdx.x * BN;
  const int m0 = blockIdx.y * BM;

  const int wave = t >> 6, lane = t & 63;
  const int quad = lane >> 4, l16 = lane & 15;
  const int wm = (wave >> 1) * 64, wn = (wave & 1) * 64;

  f32x4 acc[4][4];
#pragma unroll
  for (int i = 0; i < 4; ++i)
#pragma unroll
    for (int j = 0; j < 4; ++j) acc[i][j] = (f32x4){0.f, 0.f, 0.f, 0.f};

  float ssq[4] = {0.f, 0.f, 0.f, 0.f};

  const int ar = t >> 3;        // A: row within 32-row group (8 threads/row)
  const int ac = (t & 7) * 4;   // A: float col offset
  const int br = t >> 2;        // B: row within 64-row group (4 threads/row)
  const int bc = (t & 3) * 8;   // B: half col offset

  for (int k0 = 0; k0 < FP_DIM; k0 += BK) {
    __syncthreads();
    // stage A (fp32 -> fp16), 4 passes x 32 rows; accumulate sum-of-squares
#pragma unroll
    for (int p = 0; p < 4; ++p) {
      const int row = p * 32 + ar;
      const int gr = m0 + row;
      float4 v = {0.f, 0.f, 0.f, 0.f};
      if (gr < ND) v = *(const float4*)(data + (size_t)gr * FP_DIM + k0 + ac);
      ssq[p] += v.x * v.x + v.y * v.y + v.z * v.z + v.w * v.w;
      union { _Float16 h[4]; uint2 u; } pk;
      pk.h[0] = (_Float16)v.x; pk.h[1] = (_Float16)v.y;
      pk.h[2] = (_Float16)v.z; pk.h[3] = (_Float16)v.w;
      *(uint2*)(sA + row * LDT + ac) = pk.u;
    }
    // stage B (fp16), 2 passes x 64 rows, 16 B per thread
#pragma unroll
    for (int p = 0; p < 2; ++p) {
      const int row = p * 64 + br;
      *(uint4*)(sB + row * LDT + bc) =
          *(const uint4*)(qn + (size_t)(n0 + row) * FP_DIM + k0 + bc);
    }
    __syncthreads();

    half8 af[4], bf[4];
#pragma unroll
    for (int i = 0; i < 4; ++i)
      af[i] = *(const half8*)(sA + (wm + i * 16 + l16) * LDT + quad * 8);
#pragma unroll
    for (int j = 0; j < 4; ++j)
      bf[j] = *(const half8*)(sB + (wn + j * 16 + l16) * LDT + quad * 8);
#pragma unroll
    for (int i = 0; i < 4; ++i)
#pragma unroll
      for (int j = 0; j < 4; ++j)
        acc[i][j] = __builtin_amdgcn_mfma_f32_16x16x32_f16(af[i], bf[j], acc[i][j], 0, 0, 0);
  }

  // finalize row inv-norms: reduce ssq across the 8 threads sharing each row
#pragma unroll
  for (int p = 0; p < 4; ++p) {
    float s = ssq[p];
    s += __shfl_xor(s, 1);
    s += __shfl_xor(s, 2);
    s += __shfl_xor(s, 4);
    if ((t & 7) == 0) sNrm[p * 32 + ar] = 1.0f / fmaxf(sqrtf(s), 1e-12f);
  }
  if (t < BN) sCnt[t] = 0;
  __syncthreads();

  // epilogue: D layout (16x16): row(m) = quad*4 + reg, col(n) = lane&15
#pragma unroll
  for (int j = 0; j < 4; ++j) {
    const float tv = tq[n0 + wn + j * 16 + l16];
    int cc = 0;
#pragma unroll
    for (int i = 0; i < 4; ++i) {
      const int rbase = wm + i * 16 + quad * 4;
#pragma unroll
      for (int r = 0; r < 4; ++r) {
        const int row = rbase + r;
        if (m0 + row < ND) {
          const float qp = acc[i][j][r] * sNrm[row];
          cc += (qp >= tv) ? 1 : 0;
        }
      }
    }
    cc += __shfl_xor(cc, 16);
    cc += __shfl_xor(cc, 32);
    if (lane < 16) atomicAdd(&sCnt[wn + j * 16 + l16], cc);
  }
  __syncthreads();
  if (t < BN) atomicAdd(&out[n0 + t], sCnt[t]);
}

extern "C" void kernel_launch(void* const* d_in, const int* in_sizes, int n_in,
                              void* d_out, int out_size, void* d_ws, size_t ws_size,
                              hipStream_t stream) {
  const float* data    = (const float*)d_in[0];
  const float* queries = (const float*)d_in[1];
  const float* truths  = (const float*)d_in[2];
  const int ND = in_sizes[0] / FP_DIM;   // 50000
  const int Q  = in_sizes[1] / FP_DIM;   // 512

  _Float16* qn = (_Float16*)d_ws;                                  // Q*FP_DIM fp16
  float*    tq = (float*)((char*)d_ws + (size_t)Q * FP_DIM * 2);   // Q fp32
  int*     out = (int*)d_out;

  prep_q<<<Q, 256, 0, stream>>>(queries, truths, qn, tq, out);

  dim3 grid(Q / BN, (ND + BM - 1) / BM);   // col-tiles fast => A-tile L3 reuse
  rank_gemm<<<grid, 256, 0, stream>>>(data, qn, tq, out, ND);
}